// Round 3
// baseline (196.825 us; speedup 1.0000x reference)
//
#include <hip/hip_runtime.h>
#include <hip/hip_bf16.h>

// DirectionalPropagation1D fused: B=16, C=64, H=256, W=256, N=4096 sequences.
// 256 blocks x 4 waves; block = 16 sequences. Per step w:
//   cur = relu((bi+bs+bias) + Wi*feat_w + Ws*(g_w * cur_prev))
// State exchanged cross-wave via ping-pong LDS + ONE raw s_barrier per step
// (lgkmcnt drain only -- global traffic stays in flight across barriers; the
// r2 __syncthreads vmcnt(0) drain was the 2060 cyc/step latency bug).

typedef __attribute__((ext_vector_type(8))) short short8;
typedef __attribute__((ext_vector_type(4))) short short4v;
typedef __attribute__((ext_vector_type(2))) short short2v;
typedef __attribute__((ext_vector_type(4))) float f32x4;

union FragU { unsigned int u[4]; short8 v; };
union PkU { unsigned int u; short2v s2; };

__device__ __forceinline__ unsigned int pk2(float a, float b) {
    unsigned short lo = __bfloat16_as_ushort(__float2bfloat16(a));
    unsigned short hi = __bfloat16_as_ushort(__float2bfloat16(b));
    return (unsigned int)lo | ((unsigned int)hi << 16);
}
__device__ __forceinline__ float b2f(short x) {
    return __uint_as_float(((unsigned int)(unsigned short)x) << 16);
}

__device__ __forceinline__ int fsi(int w, int n, int c) {   // feat [w16][n16][c64]
    return (w * 1024 + n * 64 + c) ^ ((n & 7) << 3);
}
__device__ __forceinline__ int sti(int n, int c) {          // state [n16][c64]
    return (n * 64 + c) ^ ((n & 7) << 3);
}
__device__ __forceinline__ int ogi(int o, int n, int w) {   // out [o64][n16][w16]
    return (o * 256 + n * 16 + w) ^ ((((o >> 2) ^ (n >> 2)) & 3) << 2);
}

// Raw barrier: LDS drain only. Global ops pass through (counted by dataflow).
#define BAR() asm volatile("s_waitcnt lgkmcnt(0)\n\ts_barrier" ::: "memory")

template<int V> struct Ic { static constexpr int value = V; };

__global__ __launch_bounds__(256) void dp_fused_kernel(
    const float* __restrict__ feat, const float* __restrict__ conf,
    const float* __restrict__ Wi, const float* __restrict__ bi,
    const float* __restrict__ Ws, const float* __restrict__ bs,
    const float* __restrict__ bias, float* __restrict__ outp)
{
    __shared__ unsigned short fs[2][16384];  // 64 KB feat chunk bf16, ping-pong
    __shared__ unsigned short st[2][1024];   //  4 KB state bf16, ping-pong by step
    __shared__ unsigned short og[16384];     // 32 KB out staging bf16

    const int tid = threadIdx.x;
    const int lane = tid & 63;
    const int t = tid >> 6;                  // wave id = o-tile
    const int l15 = lane & 15, g4 = lane >> 4;
    const int nb = blockIdx.x;
    const int b = nb >> 4, h0 = (nb & 15) * 16;

    FragU Ai[2], As[2];
    #pragma unroll
    for (int hh = 0; hh < 2; ++hh) {
        const float* si = Wi + (16 * t + l15) * 64 + 32 * hh + g4 * 8;
        const float* ss = Ws + (16 * t + l15) * 64 + 32 * hh + g4 * 8;
        #pragma unroll
        for (int d = 0; d < 4; ++d) {
            Ai[hh].u[d] = pk2(si[2 * d], si[2 * d + 1]);
            As[hh].u[d] = pk2(ss[2 * d], ss[2 * d + 1]);
        }
    }
    float binit[4];
    #pragma unroll
    for (int r = 0; r < 4; ++r) {
        int o = 16 * t + 4 * g4 + r;
        binit[r] = bi[o] + bs[o] + bias[o];
    }

    const float* fb = feat + (size_t)b * 64 * 65536 + (size_t)h0 * 256;
    const float* gb = conf + ((size_t)(b * 256) + h0 + l15) * 256;

    f32x4 fst[2][2][4];   // feat staging regs; all indices compile-time (rule #20)
    auto load_part = [&](auto kc, auto rc, int w0n) {
        constexpr int K = decltype(kc)::value, R = decltype(rc)::value;
        const int p = tid + 256 * K; const int cp = p >> 4; const int n = p & 15;
        const float* base = fb + (size_t)(2 * cp + R) * 65536 + n * 256 + w0n;
        #pragma unroll
        for (int j = 0; j < 4; ++j)
            fst[K][R][j] = *(const f32x4*)(base + j * 4);
    };
    auto write_fs = [&](int buf) {
        #pragma unroll
        for (int k = 0; k < 2; ++k) {
            int p = tid + 256 * k; int cp = p >> 4; int n = p & 15;
            #pragma unroll
            for (int j = 0; j < 4; ++j)
                #pragma unroll
                for (int e = 0; e < 4; ++e) {
                    PkU pk; pk.u = pk2(fst[k][0][j][e], fst[k][1][j][e]);
                    *(short2v*)&fs[buf][fsi(j * 4 + e, n, 2 * cp)] = pk.s2;
                }
        }
    };
    auto dump_half = [&](auto hc, int wprev) {  // coalesced f32x4, full lines
        constexpr int H = decltype(hc)::value;
        const int n = lane >> 2, wq = lane & 3;
        #pragma unroll
        for (int k = 8 * H; k < 8 * H + 8; ++k) {
            const int o = 16 * t + k;
            short4v d = *(const short4v*)&og[ogi(o, n, wq * 4)];
            f32x4 o4 = { b2f(d.x), b2f(d.y), b2f(d.z), b2f(d.w) };
            *(f32x4*)(outp + ((size_t)(b * 64 + o) * 256 + h0 + n) * 256 + wprev + wq * 4) = o4;
        }
    };

    f32x4 gqA[4], gqB[4]; float glA, glB;
    short8 Fp[2][2];      // F register prefetch, ping-pong by step parity

    // ---- prologue ----
    load_part(Ic<0>{}, Ic<0>{}, 0); load_part(Ic<0>{}, Ic<1>{}, 0);
    load_part(Ic<1>{}, Ic<0>{}, 0); load_part(Ic<1>{}, Ic<1>{}, 0);
    #pragma unroll
    for (int q = 0; q < 4; ++q) gqA[q] = *(const f32x4*)(gb + q * 4);
    glA = gb[16];
    { short4v z = {0, 0, 0, 0}; *(short4v*)&st[0][tid * 4] = z; }
    write_fs(0);
    BAR();
    Fp[0][0] = *(const short8*)&fs[0][fsi(0, l15, g4 * 8)];
    Fp[0][1] = *(const short8*)&fs[0][fsi(0, l15, 32 + g4 * 8)];

    auto run_chunk = [&](auto pc, int cc) {
        constexpr int P = decltype(pc)::value;
        f32x4 (&gqc)[4] = P ? gqB : gqA;
        f32x4 (&gqn)[4] = P ? gqA : gqB;
        float &glc = P ? glB : glA;
        float &gln = P ? glA : glB;
        const int w0 = cc * 16;
        float curE[4];
        #pragma unroll
        for (int u = 0; u < 16; ++u) {
            // state read first (the one latency on the chain)
            short8 S0 = *(const short8*)&st[u & 1][sti(l15, g4 * 8)];
            short8 S1 = *(const short8*)&st[u & 1][sti(l15, 32 + g4 * 8)];
            // prefetch next step's F (fs is stable this chunk; u==15 reads the
            // buffer written at u==14, already barrier-separated)
            {
                const unsigned short* fsrc = (u < 15) ? fs[P] : fs[P ^ 1];
                const int wn = (u < 15) ? u + 1 : 0;
                Fp[(u + 1) & 1][0] = *(const short8*)&fsrc[fsi(wn, l15, g4 * 8)];
                Fp[(u + 1) & 1][1] = *(const short8*)&fsrc[fsi(wn, l15, 32 + g4 * 8)];
            }
            // previous-chunk out dump (reads og before any og write this chunk)
            if (u == 0 && cc > 0) dump_half(Ic<0>{}, w0 - 16);
            if (u == 1 && cc > 0) dump_half(Ic<1>{}, w0 - 16);
            // next-chunk feat loads, spread over 4 steps
            if (cc < 15) {
                if (u == 0) load_part(Ic<0>{}, Ic<0>{}, w0 + 16);
                if (u == 1) load_part(Ic<0>{}, Ic<1>{}, w0 + 16);
                if (u == 2) load_part(Ic<1>{}, Ic<0>{}, w0 + 16);
                if (u == 3) load_part(Ic<1>{}, Ic<1>{}, w0 + 16);
                if (u == 2) {
                    #pragma unroll
                    for (int q = 0; q < 4; ++q)
                        gqn[q] = *(const f32x4*)(gb + w0 + 16 + q * 4);
                    int gi = w0 + 32; if (gi > 255) gi = 255;
                    gln = gb[gi];
                }
            }

            // two independent 2-deep MFMA chains (feat half overlaps S latency)
            f32x4 accA = { binit[0], binit[1], binit[2], binit[3] };
            f32x4 accB = { 0.f, 0.f, 0.f, 0.f };
            accA = __builtin_amdgcn_mfma_f32_16x16x32_bf16(Ai[0].v, Fp[u & 1][0], accA, 0, 0, 0);
            accB = __builtin_amdgcn_mfma_f32_16x16x32_bf16(Ai[1].v, Fp[u & 1][1], accB, 0, 0, 0);
            accA = __builtin_amdgcn_mfma_f32_16x16x32_bf16(As[0].v, S0, accA, 0, 0, 0);
            accB = __builtin_amdgcn_mfma_f32_16x16x32_bf16(As[1].v, S1, accB, 0, 0, 0);
            float cur0 = fmaxf(accA[0] + accB[0], 0.f);
            float cur1 = fmaxf(accA[1] + accB[1], 0.f);
            float cur2 = fmaxf(accA[2] + accB[2], 0.f);
            float cur3 = fmaxf(accA[3] + accB[3], 0.f);

            // out staging: pack w-pairs, one b32 DS write per row on odd steps
            if ((u & 1) == 0) {
                curE[0] = cur0; curE[1] = cur1; curE[2] = cur2; curE[3] = cur3;
            } else {
                const float cc4[4] = { cur0, cur1, cur2, cur3 };
                #pragma unroll
                for (int r = 0; r < 4; ++r) {
                    PkU pk; pk.u = pk2(curE[r], cc4[r]);
                    *(short2v*)&og[ogi(16 * t + 4 * g4 + r, l15, u - 1)] = pk.s2;
                }
            }

            if (u == 14 && cc < 15) write_fs(P ^ 1);  // stage next feat chunk

            // gated state for step w+1
            if (!(cc == 15 && u == 15)) {
                float gv = (u < 15) ? gqc[(u + 1) >> 2][(u + 1) & 3] : glc;
                PkU a, c;
                a.u = pk2(cur0 * gv, cur1 * gv);
                c.u = pk2(cur2 * gv, cur3 * gv);
                short4v sv = { a.s2.x, a.s2.y, c.s2.x, c.s2.y };
                *(short4v*)&st[(u + 1) & 1][sti(l15, 16 * t + 4 * g4)] = sv;
            }
            BAR();
        }
    };

    #pragma unroll 1
    for (int c2 = 0; c2 < 8; ++c2) {
        run_chunk(Ic<0>{}, 2 * c2);
        run_chunk(Ic<1>{}, 2 * c2 + 1);
    }
    dump_half(Ic<0>{}, 240);
    dump_half(Ic<1>{}, 240);
}

extern "C" void kernel_launch(void* const* d_in, const int* in_sizes, int n_in,
                              void* d_out, int out_size, void* d_ws, size_t ws_size,
                              hipStream_t stream) {
    const float* feat = (const float*)d_in[0];
    const float* conf = (const float*)d_in[1];
    const float* Wi   = (const float*)d_in[2];
    const float* bi   = (const float*)d_in[3];
    const float* Ws   = (const float*)d_in[4];
    const float* bs   = (const float*)d_in[5];
    const float* bias = (const float*)d_in[6];
    float* out = (float*)d_out;
    (void)d_ws; (void)ws_size; (void)in_sizes; (void)n_in; (void)out_size;

    dp_fused_kernel<<<256, 256, 0, stream>>>(feat, conf, Wi, bi, Ws, bs, bias, out);
}

// Round 5
// 184.328 us; speedup vs baseline: 1.0678x; 1.0678x over previous
//
#include <hip/hip_runtime.h>
#include <hip/hip_bf16.h>

// DirectionalPropagation1D fused v5: B=16, C=64, H=256, W=256, N=4096 seqs.
// 256 blocks x 4 waves. Wave 0 runs the full 64-channel recurrence with the
// state HELD IN REGISTERS: the recurrence MFMA's k-order is permuted via
//   K(h,g4,j) = 16*(2h + (j>>2)) + 4*g4 + (j&3)
// (absorbed into the constant Ws A-fragments), so each lane's D-fragment IS
// its next-step B-fragment -- no cross-lane, no LDS, no barrier on the chain.
// Waves 1-2 stage feat (f32->bf16) into double-buffered LDS; wave 3 drains
// the bf16 out staging to coalesced f32x4 global stores. One lgkm-only
// barrier per 16-step chunk (17 total).
// v5 fix vs v4: og write uses ogi() directly (v4 hand-expanded the XOR
// swizzle into an ADD, scrambling w-quads -- both sides must be the same
// pure function; rule 21).

typedef __attribute__((ext_vector_type(8))) short short8;
typedef __attribute__((ext_vector_type(4))) short short4v;
typedef __attribute__((ext_vector_type(2))) short short2v;
typedef __attribute__((ext_vector_type(4))) float f32x4;

union FragU { unsigned int u[4]; short8 v; };
union PkU { unsigned int u; short2v s2; };

__device__ __forceinline__ unsigned int pk2(float a, float b) {
    unsigned short lo = __bfloat16_as_ushort(__float2bfloat16(a));
    unsigned short hi = __bfloat16_as_ushort(__float2bfloat16(b));
    return (unsigned int)lo | ((unsigned int)hi << 16);
}
__device__ __forceinline__ float b2f(short x) {
    return __uint_as_float(((unsigned int)(unsigned short)x) << 16);
}

// feat staging [w16][n16][c64] bf16, XOR-swizzled.
__device__ __forceinline__ int fsi(int w, int n, int c) {
    return (w * 1024 + n * 64 + c) ^ ((n & 7) << 3);
}
// out staging [o64][n16][w16] bf16, XOR-swizzled (same function both sides).
__device__ __forceinline__ int ogi(int o, int n, int w) {
    return (o * 256 + n * 16 + w) ^ ((((o >> 2) ^ (n >> 2)) & 3) << 2);
}

// LDS-only barrier: global traffic stays in flight across it.
#define BAR() asm volatile("s_waitcnt lgkmcnt(0)\n\ts_barrier" ::: "memory")

template<int V> struct Ic { static constexpr int value = V; };

__global__ __launch_bounds__(256, 1) void dp_v5_kernel(
    const float* __restrict__ feat, const float* __restrict__ conf,
    const float* __restrict__ Wi, const float* __restrict__ bi,
    const float* __restrict__ Ws, const float* __restrict__ bs,
    const float* __restrict__ bias, float* __restrict__ outp)
{
    __shared__ unsigned short fs[2][16384];  // 64 KB feat bf16, ping-pong
    __shared__ unsigned short og[2][16384];  // 64 KB out bf16, ping-pong

    const int tid = threadIdx.x;
    const int lane = tid & 63;
    const int wid = tid >> 6;
    const int l15 = lane & 15, g4 = lane >> 4;
    const int nb = blockIdx.x;
    const int b = nb >> 4, h0 = (nb & 15) * 16;

    const float* fb = feat + (size_t)b * 64 * 65536 + (size_t)h0 * 256;

    if (wid == 0) {
        // ================= recurrence wave =================
        const float* gb = conf + ((size_t)(b * 256) + h0 + l15) * 256;

        // Ai: natural k-order. As: permuted columns K(h,g4,j).
        FragU Ai[4][2], As[4][2];
        #pragma unroll
        for (int t = 0; t < 4; ++t)
            #pragma unroll
            for (int h = 0; h < 2; ++h) {
                const float* si = Wi + (16 * t + l15) * 64 + 32 * h + g4 * 8;
                const float* ss = Ws + (16 * t + l15) * 64;
                #pragma unroll
                for (int d = 0; d < 4; ++d) {
                    Ai[t][h].u[d] = pk2(si[2 * d], si[2 * d + 1]);
                    const int c0 = 16 * (2 * h + (d >> 1)) + 4 * g4 + 2 * (d & 1);
                    As[t][h].u[d] = pk2(ss[c0], ss[c0 + 1]);
                }
            }
        f32x4 binit[4];
        #pragma unroll
        for (int t = 0; t < 4; ++t)
            #pragma unroll
            for (int r = 0; r < 4; ++r) {
                int o = 16 * t + 4 * g4 + r;
                binit[t][r] = bi[o] + bs[o] + bias[o];
            }

        f32x4 gqA[4], gqB[4];
        #pragma unroll
        for (int q = 0; q < 4; ++q) gqA[q] = *(const f32x4*)(gb + 4 * q);

        FragU S0, S1;
        #pragma unroll
        for (int d = 0; d < 4; ++d) { S0.u[d] = 0u; S1.u[d] = 0u; }

        float curE[4][4];

        BAR();  // matches producers' post-prologue barrier

        auto run_chunk = [&](auto pc, int cc) {
            constexpr int P = decltype(pc)::value;
            f32x4 (&gqc)[4] = P ? gqB : gqA;
            f32x4 (&gqn)[4] = P ? gqA : gqB;
            const int w0 = cc * 16;
            #pragma unroll
            for (int u = 0; u < 16; ++u) {
                short8 F0 = *(const short8*)&fs[P][fsi(u, l15, 8 * g4)];
                short8 F1 = *(const short8*)&fs[P][fsi(u, l15, 32 + 8 * g4)];

                if (u == 2 && cc < 15) {
                    #pragma unroll
                    for (int q = 0; q < 4; ++q)
                        gqn[q] = *(const f32x4*)(gb + w0 + 16 + 4 * q);
                }

                f32x4 a0 = binit[0], a1 = binit[1], a2 = binit[2], a3 = binit[3];
                a0 = __builtin_amdgcn_mfma_f32_16x16x32_bf16(Ai[0][0].v, F0, a0, 0, 0, 0);
                a1 = __builtin_amdgcn_mfma_f32_16x16x32_bf16(Ai[1][0].v, F0, a1, 0, 0, 0);
                a2 = __builtin_amdgcn_mfma_f32_16x16x32_bf16(Ai[2][0].v, F0, a2, 0, 0, 0);
                a3 = __builtin_amdgcn_mfma_f32_16x16x32_bf16(Ai[3][0].v, F0, a3, 0, 0, 0);
                a0 = __builtin_amdgcn_mfma_f32_16x16x32_bf16(Ai[0][1].v, F1, a0, 0, 0, 0);
                a1 = __builtin_amdgcn_mfma_f32_16x16x32_bf16(Ai[1][1].v, F1, a1, 0, 0, 0);
                a2 = __builtin_amdgcn_mfma_f32_16x16x32_bf16(Ai[2][1].v, F1, a2, 0, 0, 0);
                a3 = __builtin_amdgcn_mfma_f32_16x16x32_bf16(Ai[3][1].v, F1, a3, 0, 0, 0);
                a0 = __builtin_amdgcn_mfma_f32_16x16x32_bf16(As[0][0].v, S0.v, a0, 0, 0, 0);
                a1 = __builtin_amdgcn_mfma_f32_16x16x32_bf16(As[1][0].v, S0.v, a1, 0, 0, 0);
                a2 = __builtin_amdgcn_mfma_f32_16x16x32_bf16(As[2][0].v, S0.v, a2, 0, 0, 0);
                a3 = __builtin_amdgcn_mfma_f32_16x16x32_bf16(As[3][0].v, S0.v, a3, 0, 0, 0);
                a0 = __builtin_amdgcn_mfma_f32_16x16x32_bf16(As[0][1].v, S1.v, a0, 0, 0, 0);
                a1 = __builtin_amdgcn_mfma_f32_16x16x32_bf16(As[1][1].v, S1.v, a1, 0, 0, 0);
                a2 = __builtin_amdgcn_mfma_f32_16x16x32_bf16(As[2][1].v, S1.v, a2, 0, 0, 0);
                a3 = __builtin_amdgcn_mfma_f32_16x16x32_bf16(As[3][1].v, S1.v, a3, 0, 0, 0);

                float cur[4][4];
                #pragma unroll
                for (int r = 0; r < 4; ++r) {
                    cur[0][r] = fmaxf(a0[r], 0.f);
                    cur[1][r] = fmaxf(a1[r], 0.f);
                    cur[2][r] = fmaxf(a2[r], 0.f);
                    cur[3][r] = fmaxf(a3[r], 0.f);
                }

                // out staging: pack w-pairs, 16 b32 DS writes on odd steps.
                // NOTE: full ogi() on the write side -- must match reader.
                if ((u & 1) == 0) {
                    #pragma unroll
                    for (int t = 0; t < 4; ++t)
                        #pragma unroll
                        for (int r = 0; r < 4; ++r) curE[t][r] = cur[t][r];
                } else {
                    #pragma unroll
                    for (int t = 0; t < 4; ++t)
                        #pragma unroll
                        for (int r = 0; r < 4; ++r) {
                            PkU pk; pk.u = pk2(curE[t][r], cur[t][r]);
                            *(short2v*)&og[P][ogi(16 * t + 4 * g4 + r, l15, u - 1)] = pk.s2;
                        }
                }

                // rebuild state fragments for step w+1 (lane-local!)
                if (!(cc == 15 && u == 15)) {
                    float gv = (u < 15) ? gqc[(u + 1) >> 2][(u + 1) & 3] : gqn[0][0];
                    float g0[4], g1[4], g2[4], g3[4];
                    #pragma unroll
                    for (int r = 0; r < 4; ++r) {
                        g0[r] = cur[0][r] * gv; g1[r] = cur[1][r] * gv;
                        g2[r] = cur[2][r] * gv; g3[r] = cur[3][r] * gv;
                    }
                    S0.u[0] = pk2(g0[0], g0[1]); S0.u[1] = pk2(g0[2], g0[3]);
                    S0.u[2] = pk2(g1[0], g1[1]); S0.u[3] = pk2(g1[2], g1[3]);
                    S1.u[0] = pk2(g2[0], g2[1]); S1.u[1] = pk2(g2[2], g2[3]);
                    S1.u[2] = pk2(g3[0], g3[1]); S1.u[3] = pk2(g3[2], g3[3]);
                }
            }
            BAR();  // end of chunk
        };

        #pragma unroll 1
        for (int c2 = 0; c2 < 8; ++c2) {
            run_chunk(Ic<0>{}, 2 * c2);
            run_chunk(Ic<1>{}, 2 * c2 + 1);
        }
    } else if (wid <= 2) {
        // ================= feat stagers (waves 1,2) =================
        const int cb2 = (wid - 1) * 16;   // c-pair base: wave1 c0..31, wave2 c32..63
        const int n = lane & 15;

        auto stage = [&](int buf, int w0) {
            f32x4 ra[4][2][4];  // [unit][row][w-quad], all statically indexed
            #pragma unroll
            for (int pi = 0; pi < 4; ++pi) {
                const int cp = cb2 + 4 * pi + g4;
                const float* p0 = fb + (size_t)(2 * cp) * 65536 + n * 256 + w0;
                #pragma unroll
                for (int row = 0; row < 2; ++row)
                    #pragma unroll
                    for (int q = 0; q < 4; ++q)
                        ra[pi][row][q] = *(const f32x4*)(p0 + row * 65536 + 4 * q);
            }
            #pragma unroll
            for (int pi = 0; pi < 4; ++pi) {
                const int cp = cb2 + 4 * pi + g4;
                #pragma unroll
                for (int q = 0; q < 4; ++q)
                    #pragma unroll
                    for (int e = 0; e < 4; ++e) {
                        PkU pk; pk.u = pk2(ra[pi][0][q][e], ra[pi][1][q][e]);
                        *(short2v*)&fs[buf][fsi(4 * q + e, n, 2 * cp)] = pk.s2;
                    }
            }
        };

        stage(0, 0);
        BAR();
        #pragma unroll 1
        for (int cc = 0; cc < 16; ++cc) {
            if (cc < 15) stage((cc + 1) & 1, (cc + 1) * 16);
            BAR();
        }
    } else {
        // ================= out drainer (wave 3) =================
        const int n = (lane >> 2) & 15, wq = lane & 3;
        float* const ob = outp + ((size_t)(b * 64) * 256 + h0 + n) * 256 + 4 * wq;

        auto drain = [&](int buf, int wpr) {
            #pragma unroll 8
            for (int o = 0; o < 64; ++o) {
                short4v d = *(const short4v*)&og[buf][ogi(o, n, 4 * wq)];
                f32x4 o4 = { b2f(d.x), b2f(d.y), b2f(d.z), b2f(d.w) };
                *(f32x4*)(ob + (size_t)o * 65536 + wpr) = o4;
            }
        };

        BAR();
        #pragma unroll 1
        for (int cc = 0; cc < 16; ++cc) {
            if (cc > 0) drain((cc - 1) & 1, (cc - 1) * 16);
            BAR();
        }
        drain(1, 240);  // chunk 15
    }
}

extern "C" void kernel_launch(void* const* d_in, const int* in_sizes, int n_in,
                              void* d_out, int out_size, void* d_ws, size_t ws_size,
                              hipStream_t stream) {
    const float* feat = (const float*)d_in[0];
    const float* conf = (const float*)d_in[1];
    const float* Wi   = (const float*)d_in[2];
    const float* bi   = (const float*)d_in[3];
    const float* Ws   = (const float*)d_in[4];
    const float* bs   = (const float*)d_in[5];
    const float* bias = (const float*)d_in[6];
    float* out = (float*)d_out;
    (void)d_ws; (void)ws_size; (void)in_sizes; (void)n_in; (void)out_size;

    dp_v5_kernel<<<256, 256, 0, stream>>>(feat, conf, Wi, bi, Ws, bs, bias, out);
}